// Round 2
// baseline (523.381 us; speedup 1.0000x reference)
//
#include <hip/hip_runtime.h>
#include <hip/hip_bf16.h>

#define NHID 64
#define NT   63
#define NBD  512
#define WSTR 68   // W LDS row stride (floats): conflict-free b128 for o in {p, p+32}
#define HSTR 68   // h LDS row stride: rows hold 64 channels (was 36 -> row aliasing BUG)
#define XSTR 34   // x LDS row stride
#define ASTR 130  // FC a-tile LDS stride (bf16 elems)

__device__ __forceinline__ float tanh_fast(float x) {
    float a = fabsf(x);
    float e = __expf(2.0f * a);              // inf-safe
    float t = 1.0f - 2.0f / (e + 1.0f);      // in [0,1], no NaN for large a
    return copysignf(t, x);
}

__device__ __forceinline__ float bf2f(unsigned int u16) {
    return __uint_as_float(u16 << 16);
}

// One block per (direction, batch). Runs steps t0 .. t0+tch-1 of the skewed
// scan, loading h-state from hstate (zeros if t0==0) and storing it back.
// Activations stored bf16 in ring layout [tt][bd][o*32+r].
__global__ __launch_bounds__(256, 2) void k_rnn(
    const float* __restrict__ x,
    const float* __restrict__ w_in,
    const float* __restrict__ b_in,
    const float* __restrict__ w_state,
    const float* __restrict__ b_state,
    __hip_bfloat16* __restrict__ acts,
    float* __restrict__ hstate,
    int t0, int tch)
{
    __shared__ float Wup[NHID * WSTR];
    __shared__ float Wsm[NHID * WSTR];
    __shared__ float hbuf[33 * HSTR];   // row 0 = permanent zero row (h_up at r=0)
    __shared__ float xs[32 * XSTR];

    const int tid = threadIdx.x;
    const int bd  = blockIdx.x;
    const int d   = bd >> 7;
    const int b   = bd & 127;

    // w_state is (o, i, 2): s=0 -> w_up, s=1 -> w_same
    const float2* w2 = (const float2*)w_state;
    for (int idx = tid; idx < NHID * NHID; idx += 256) {
        const int o = idx >> 6, i = idx & 63;
        const float2 v = w2[idx];
        Wup[o * WSTR + i] = v.x;
        Wsm[o * WSTR + i] = v.y;
    }

    // h-state init: zeros at t0==0, else restore from hstate[bd]
    const float* hs = hstate + (size_t)bd * 2048;
    for (int m = tid; m < 33 * HSTR; m += 256) {
        const int row = m / HSTR, col = m - row * HSTR;
        float v = 0.0f;
        if (t0 > 0 && row >= 1 && col < 64) v = hs[(row - 1) * 64 + col];
        hbuf[m] = v;
    }

    // direction flips: d1 flips rows, d2 flips cols, d3 both
    const bool flr = (d & 1) != 0;
    const bool flc = (d & 2) != 0;
    const float* xb = x + (size_t)b * 1024;
    for (int idx = tid; idx < 1024; idx += 256) {
        const int r = idx >> 5, c = idx & 31;
        const int rr = flr ? 31 - r : r;
        const int cc = flc ? 31 - c : c;
        xs[r * XSTR + c] = xb[rr * 32 + cc];
    }

    const int p  = tid >> 3;   // o-pair {p, p+32}
    const int rg = tid & 7;    // r-group {rg, rg+8, rg+16, rg+24}
    const float bias0 = b_in[p] + b_state[p];
    const float bias1 = b_in[p + 32] + b_state[p + 32];
    const float win0 = w_in[p];
    const float win1 = w_in[p + 32];

    __syncthreads();

    for (int tt = 0; tt < tch; ++tt) {
        const int t = t0 + tt;
        float s0[4] = {0.f, 0.f, 0.f, 0.f};
        float s1[4] = {0.f, 0.f, 0.f, 0.f};
        #pragma unroll 2
        for (int i = 0; i < NHID; i += 4) {
            const float4 wu0 = *(const float4*)&Wup[p * WSTR + i];
            const float4 wu1 = *(const float4*)&Wup[(p + 32) * WSTR + i];
            const float4 wm0 = *(const float4*)&Wsm[p * WSTR + i];
            const float4 wm1 = *(const float4*)&Wsm[(p + 32) * WSTR + i];
            #pragma unroll
            for (int k = 0; k < 4; ++k) {
                const int r = rg + 8 * k;
                const float4 hu = *(const float4*)&hbuf[r * HSTR + i];        // h[r-1]
                const float4 hc = *(const float4*)&hbuf[(r + 1) * HSTR + i];  // h[r]
                s0[k] += wu0.x * hu.x + wu0.y * hu.y + wu0.z * hu.z + wu0.w * hu.w
                       + wm0.x * hc.x + wm0.y * hc.y + wm0.z * hc.z + wm0.w * hc.w;
                s1[k] += wu1.x * hu.x + wu1.y * hu.y + wu1.z * hu.z + wu1.w * hu.w
                       + wm1.x * hc.x + wm1.y * hc.y + wm1.z * hc.z + wm1.w * hc.w;
            }
        }
        float xv[4];
        #pragma unroll
        for (int k = 0; k < 4; ++k) {
            const int r = rg + 8 * k;
            const int c = t - r;
            xv[k] = (c >= 0 && c < 32) ? xs[r * XSTR + c] : 0.0f;
        }
        __syncthreads();   // all reads of hbuf done before overwrite
        __hip_bfloat16* act_t = acts + ((size_t)tt * NBD + bd) * 2048;
        #pragma unroll
        for (int k = 0; k < 4; ++k) {
            const int r = rg + 8 * k;
            const float h0 = tanh_fast(s0[k] + bias0 + win0 * xv[k]);
            const float h1 = tanh_fast(s1[k] + bias1 + win1 * xv[k]);
            hbuf[(r + 1) * HSTR + p]      = h0;
            hbuf[(r + 1) * HSTR + p + 32] = h1;
            act_t[p * 32 + r]        = __float2bfloat16(h0);
            act_t[(p + 32) * 32 + r] = __float2bfloat16(h1);
        }
        __syncthreads();   // new h visible before next step's reads
    }

    // persist h-state for the next chunk (loop ends with a barrier -> safe)
    float* hso = hstate + (size_t)bd * 2048;
    for (int m = tid; m < 2048; m += 256) {
        const int r = m >> 6, ch = m & 63;
        hso[m] = hbuf[(r + 1) * HSTR + ch];
    }
}

// FC partials: one block per (tt, d, q4). Handles oc in [q4*4, q4*4+4),
// staging 128b x 128(o,r) bf16 act tiles in LDS plus the matching w_fc rows
// (invalid skew cells zeroed). Deterministic partial per block.
__global__ __launch_bounds__(256, 2) void k_fc(
    const __hip_bfloat16* __restrict__ acts,
    const float* __restrict__ w_fc,
    float* __restrict__ partial,
    int t0)
{
    __shared__ unsigned short a_s[128 * ASTR];
    __shared__ float w_s[10 * 130];
    __shared__ float red[4 * 128 * 10];

    const int tid = threadIdx.x;
    const int blk = blockIdx.x;
    const int q4  = blk & 3;
    const int sub = blk >> 2;
    const int tt  = sub >> 2;
    const int d   = sub & 3;
    const int t   = t0 + tt;

    const int bloc = tid & 63;   // handles b = bloc and bloc+64
    const int q = tid >> 6;      // j-quarter

    float acc0[10], acc1[10];
    #pragma unroll
    for (int n = 0; n < 10; ++n) { acc0[n] = 0.0f; acc1[n] = 0.0f; }

    const unsigned short* abase =
        (const unsigned short*)acts + ((size_t)tt * NBD + (size_t)d * 128) * 2048;

    for (int oc = q4 * 4; oc < q4 * 4 + 4; ++oc) {
        __syncthreads();   // previous tile fully consumed
        #pragma unroll
        for (int it = 0; it < 8; ++it) {
            const int e = (it * 256 + tid) * 8;
            const int bb = e >> 7, j = e & 127;
            const uint4 v = *(const uint4*)(abase + (size_t)bb * 2048 + oc * 128 + j);
            unsigned int* dst = (unsigned int*)&a_s[bb * ASTR + j];
            dst[0] = v.x; dst[1] = v.y; dst[2] = v.z; dst[3] = v.w;
        }
        if (tid < 128) {
            const int j = tid;
            const int o = oc * 4 + (j >> 5);
            const int r = j & 31;
            const int c = t - r;
            const bool valid = (c >= 0) && (c < 32);
            const size_t row = ((size_t)(d * 64 + o) << 10) + (size_t)(r << 5) + (valid ? c : 0);
            #pragma unroll
            for (int n = 0; n < 10; ++n)
                w_s[n * 130 + j] = valid ? w_fc[row * 10 + n] : 0.0f;
        }
        __syncthreads();
        #pragma unroll 4
        for (int jj = 0; jj < 32; jj += 2) {
            const int j = q * 32 + jj;
            const unsigned int va = *(const unsigned int*)&a_s[bloc * ASTR + j];
            const unsigned int vb = *(const unsigned int*)&a_s[(bloc + 64) * ASTR + j];
            const float a00 = bf2f(va & 0xffffu), a01 = bf2f(va >> 16);
            const float a10 = bf2f(vb & 0xffffu), a11 = bf2f(vb >> 16);
            #pragma unroll
            for (int n = 0; n < 10; ++n) {
                const float2 wv = *(const float2*)&w_s[n * 130 + j];
                acc0[n] += a00 * wv.x + a01 * wv.y;
                acc1[n] += a10 * wv.x + a11 * wv.y;
            }
        }
    }
    __syncthreads();
    #pragma unroll
    for (int n = 0; n < 10; ++n) {
        red[(q * 128 + bloc) * 10 + n]      = acc0[n];
        red[(q * 128 + bloc + 64) * 10 + n] = acc1[n];
    }
    __syncthreads();
    for (int m = tid; m < 1280; m += 256) {
        const int bb = m / 10, n = m % 10;
        const float sum = red[bb * 10 + n] + red[(128 + bb) * 10 + n]
                        + red[(256 + bb) * 10 + n] + red[(384 + bb) * 10 + n];
        partial[((size_t)(t * 4 + d) * 4 + q4) * 1280 + m] = sum;
    }
}

// Final reduce over 1008 partial slots + bias + log_softmax. One block per batch row.
__global__ __launch_bounds__(256) void k_red(
    const float* __restrict__ partial,
    const float* __restrict__ b_fc,
    float* __restrict__ out)
{
    __shared__ float red2[250];
    __shared__ float lgs[10];
    __shared__ float lse;
    const int b = blockIdx.x;
    const int tid = threadIdx.x;
    if (tid < 250) {
        const int cs = tid / 10, n = tid % 10;
        float acc = 0.0f;
        for (int c = cs; c < 1008; c += 25)
            acc += partial[(size_t)c * 1280 + b * 10 + n];
        red2[tid] = acc;
    }
    __syncthreads();
    if (tid < 10) {
        float s = b_fc[tid];
        #pragma unroll
        for (int cs = 0; cs < 25; ++cs) s += red2[cs * 10 + tid];
        lgs[tid] = s;
    }
    __syncthreads();
    if (tid == 0) {
        float m = lgs[0];
        for (int n = 1; n < 10; ++n) m = fmaxf(m, lgs[n]);
        float ssum = 0.0f;
        for (int n = 0; n < 10; ++n) ssum += __expf(lgs[n] - m);
        lse = m + __logf(ssum);
    }
    __syncthreads();
    if (tid < 10) out[b * 10 + tid] = lgs[tid] - lse;
}

extern "C" void kernel_launch(void* const* d_in, const int* in_sizes, int n_in,
                              void* d_out, int out_size, void* d_ws, size_t ws_size,
                              hipStream_t stream)
{
    const float* x       = (const float*)d_in[0];
    const float* w_in    = (const float*)d_in[1];
    const float* b_in    = (const float*)d_in[2];
    const float* w_state = (const float*)d_in[3];
    const float* b_state = (const float*)d_in[4];
    const float* w_fc    = (const float*)d_in[5];
    const float* b_fc    = (const float*)d_in[6];
    float* out = (float*)d_out;

    const size_t HSTATE_BYTES  = (size_t)NBD * 2048 * 4;          // 4 MB fp32 h-state
    const size_t PARTIAL_BYTES = (size_t)1008 * 1280 * 4;         // 5.2 MB
    float* hstate  = (float*)d_ws;
    float* partial = (float*)((char*)d_ws + HSTATE_BYTES);
    __hip_bfloat16* acts = (__hip_bfloat16*)((char*)d_ws + HSTATE_BYTES + PARTIAL_BYTES);

    // pick the largest t-chunk whose act ring fits in ws (63 -> monolithic)
    const int tch_opts[4] = {63, 9, 3, 1};
    int tch = 1;
    for (int i = 0; i < 4; ++i) {
        const size_t need = HSTATE_BYTES + PARTIAL_BYTES
                          + (size_t)tch_opts[i] * NBD * 2048 * 2;
        if (ws_size >= need) { tch = tch_opts[i]; break; }
    }
    const int nch = NT / tch;

    for (int c = 0; c < nch; ++c) {
        k_rnn<<<512, 256, 0, stream>>>(x, w_in, b_in, w_state, b_state,
                                       acts, hstate, c * tch, tch);
        k_fc <<<tch * 16, 256, 0, stream>>>(acts, w_fc, partial, c * tch);
    }
    k_red<<<128, 256, 0, stream>>>(partial, b_fc, out);
}

// Round 3
// 134.131 us; speedup vs baseline: 3.9020x; 3.9020x over previous
//
#include <hip/hip_runtime.h>
#include <hip/hip_bf16.h>

#define NHID 64
#define NT   63
#define NBD  512
#define HLDS_STR 72   // shorts per h_lds row (144 B = 16*9): quarter-wave b128 reads 2-way (free)
#define XSTR 35       // floats per xs row: skew read addr = 34r+t -> banks spread
#define ASTR 130      // FC a-tile LDS stride (bf16 elems)

typedef __attribute__((ext_vector_type(8))) short bf16x8;
typedef __attribute__((ext_vector_type(4))) float f32x4;

__device__ __forceinline__ float tanh_fast(float x) {
    float a = fabsf(x);
    float e = __expf(2.0f * a);              // inf-safe
    float t = 1.0f - 2.0f / (e + 1.0f);      // in [0,1], no NaN for large a
    return copysignf(t, x);
}

__device__ __forceinline__ unsigned short f2bf(float f) {   // RNE, matches __float2bfloat16
    unsigned int u = __float_as_uint(f);
    return (unsigned short)((u + 0x7fffu + ((u >> 16) & 1u)) >> 16);
}
__device__ __forceinline__ float bf2f_s(unsigned short s) {
    return __uint_as_float(((unsigned int)s) << 16);
}
__device__ __forceinline__ float bf2f(unsigned int u16) {
    return __uint_as_float(u16 << 16);
}

// MFMA recurrence: 1 block = 1 (dir,batch) sequence; 4 waves = (o-half wp) x (r-half nt).
// Per wave per step: 4 ds_read_b128 (B frags) + 16 mfma_16x16x32_bf16 (W hi/lo split,
// held in registers) + 8 tanh + 2 ds_write_b64 + 2 global dwordx2.
// h in LDS bf16, row stride 72 shorts, permanent zero row at index 0 (h_up at r=0).
// acts layout: [tt][bd][r*64 + o] bf16.
__global__ __launch_bounds__(256, 2) void k_rnn(
    const float* __restrict__ x,
    const float* __restrict__ w_in,
    const float* __restrict__ b_in,
    const float* __restrict__ w_state,
    const float* __restrict__ b_state,
    __hip_bfloat16* __restrict__ acts,
    unsigned short* __restrict__ hstate,
    int t0, int tch)
{
    __shared__ __align__(16) unsigned short h_lds[33 * HLDS_STR];
    __shared__ float xs[32 * XSTR];

    const int tid = threadIdx.x;
    const int bd  = blockIdx.x;
    const int d   = bd >> 7;
    const int b   = bd & 127;
    const int lane = tid & 63;
    const int wave = tid >> 6;
    const int wp = wave & 1;     // o-half: o in [wp*32, wp*32+32)
    const int nt = wave >> 1;    // r-half: r in [nt*16, nt*16+16)
    const int n  = lane & 15;
    const int g  = lane >> 4;

    // ---- stage x with direction flips ----
    const bool flr = (d & 1) != 0;
    const bool flc = (d & 2) != 0;
    const float* xb = x + (size_t)b * 1024;
    for (int idx = tid; idx < 1024; idx += 256) {
        const int r = idx >> 5, c = idx & 31;
        xs[r * XSTR + c] = xb[(flr ? 31 - r : r) * 32 + (flc ? 31 - c : c)];
    }

    // ---- zero h_lds (incl. permanent zero row + pad chans), then restore ----
    for (int m2 = tid; m2 < (33 * HLDS_STR) / 2; m2 += 256)
        ((unsigned int*)h_lds)[m2] = 0u;
    __syncthreads();
    if (t0 > 0) {
        const unsigned short* hs = hstate + (size_t)bd * 2048;
        const int r = tid >> 3, ch = (tid & 7) * 8;
        *(uint4*)&h_lds[(r + 1) * HLDS_STR + ch] = *(const uint4*)&hs[r * 64 + ch];
    }

    // ---- A fragments (weights), hi/lo bf16 split, loaded once ----
    // A row m = lane&15; k = g*8 + j within a 32-wide k-tile.
    // k-tiles: 0: up chans 0-31, 1: up 32-63, 2: same 0-31, 3: same 32-63.
    bf16x8 a_hi[2][4], a_lo[2][4];
    #pragma unroll
    for (int wl = 0; wl < 2; ++wl) {
        const int o = wp * 32 + wl * 16 + n;
        #pragma unroll
        for (int kt = 0; kt < 4; ++kt) {
            const int s  = kt >> 1;
            const int cb = (kt & 1) * 32 + g * 8;
            bf16x8 hi8, lo8;
            #pragma unroll
            for (int j = 0; j < 8; ++j) {
                const float w = w_state[((size_t)o * 64 + cb + j) * 2 + s];
                const unsigned short h16 = f2bf(w);
                hi8[j] = (short)h16;
                lo8[j] = (short)f2bf(w - bf2f_s(h16));
            }
            a_hi[wl][kt] = hi8;
            a_lo[wl][kt] = lo8;
        }
    }

    // bias / w_in per C-fragment slot: o = wp*32 + wl*16 + g*4 + j
    float biasr[2][4], winr[2][4];
    #pragma unroll
    for (int wl = 0; wl < 2; ++wl)
        #pragma unroll
        for (int j = 0; j < 4; ++j) {
            const int o = wp * 32 + wl * 16 + g * 4 + j;
            biasr[wl][j] = b_in[o] + b_state[o];
            winr[wl][j]  = w_in[o];
        }

    const int r_out = nt * 16 + n;   // this lane's r (B col & C col)
    const unsigned short* hup = &h_lds[r_out * HLDS_STR + g * 8];  // h[r-1] (zero row at 0)

    __syncthreads();

    for (int tt = 0; tt < tch; ++tt) {
        const int t = t0 + tt;
        // B fragments: kt0/1 from row r (= h[r-1]), kt2/3 from row r+1 (= h[r])
        const bf16x8 b0 = *(const bf16x8*)(hup);
        const bf16x8 b1 = *(const bf16x8*)(hup + 32);
        const bf16x8 b2 = *(const bf16x8*)(hup + HLDS_STR);
        const bf16x8 b3 = *(const bf16x8*)(hup + HLDS_STR + 32);

        f32x4 a0h = {0,0,0,0}, a0l = {0,0,0,0}, a1h = {0,0,0,0}, a1l = {0,0,0,0};
        a0h = __builtin_amdgcn_mfma_f32_16x16x32_bf16(a_hi[0][0], b0, a0h, 0, 0, 0);
        a1h = __builtin_amdgcn_mfma_f32_16x16x32_bf16(a_hi[1][0], b0, a1h, 0, 0, 0);
        a0l = __builtin_amdgcn_mfma_f32_16x16x32_bf16(a_lo[0][0], b0, a0l, 0, 0, 0);
        a1l = __builtin_amdgcn_mfma_f32_16x16x32_bf16(a_lo[1][0], b0, a1l, 0, 0, 0);
        a0h = __builtin_amdgcn_mfma_f32_16x16x32_bf16(a_hi[0][1], b1, a0h, 0, 0, 0);
        a1h = __builtin_amdgcn_mfma_f32_16x16x32_bf16(a_hi[1][1], b1, a1h, 0, 0, 0);
        a0l = __builtin_amdgcn_mfma_f32_16x16x32_bf16(a_lo[0][1], b1, a0l, 0, 0, 0);
        a1l = __builtin_amdgcn_mfma_f32_16x16x32_bf16(a_lo[1][1], b1, a1l, 0, 0, 0);
        a0h = __builtin_amdgcn_mfma_f32_16x16x32_bf16(a_hi[0][2], b2, a0h, 0, 0, 0);
        a1h = __builtin_amdgcn_mfma_f32_16x16x32_bf16(a_hi[1][2], b2, a1h, 0, 0, 0);
        a0l = __builtin_amdgcn_mfma_f32_16x16x32_bf16(a_lo[0][2], b2, a0l, 0, 0, 0);
        a1l = __builtin_amdgcn_mfma_f32_16x16x32_bf16(a_lo[1][2], b2, a1l, 0, 0, 0);
        a0h = __builtin_amdgcn_mfma_f32_16x16x32_bf16(a_hi[0][3], b3, a0h, 0, 0, 0);
        a1h = __builtin_amdgcn_mfma_f32_16x16x32_bf16(a_hi[1][3], b3, a1h, 0, 0, 0);
        a0l = __builtin_amdgcn_mfma_f32_16x16x32_bf16(a_lo[0][3], b3, a0l, 0, 0, 0);
        a1l = __builtin_amdgcn_mfma_f32_16x16x32_bf16(a_lo[1][3], b3, a1l, 0, 0, 0);

        const int c = t - r_out;
        const float xv = (c >= 0 && c < 32) ? xs[r_out * XSTR + c] : 0.0f;

        __syncthreads();   // all waves' B reads done before h overwrite

        unsigned short* wr = &h_lds[(r_out + 1) * HLDS_STR];
        unsigned short* act_t = (unsigned short*)acts
                              + ((size_t)tt * NBD + bd) * 2048 + r_out * 64;
        {   // wl = 0
            const unsigned short q0 = f2bf(tanh_fast(a0h[0] + a0l[0] + biasr[0][0] + winr[0][0] * xv));
            const unsigned short q1 = f2bf(tanh_fast(a0h[1] + a0l[1] + biasr[0][1] + winr[0][1] * xv));
            const unsigned short q2 = f2bf(tanh_fast(a0h[2] + a0l[2] + biasr[0][2] + winr[0][2] * xv));
            const unsigned short q3 = f2bf(tanh_fast(a0h[3] + a0l[3] + biasr[0][3] + winr[0][3] * xv));
            uint2 pk;
            pk.x = (unsigned int)q0 | ((unsigned int)q1 << 16);
            pk.y = (unsigned int)q2 | ((unsigned int)q3 << 16);
            const int cb = wp * 32 + g * 4;
            *(uint2*)&wr[cb] = pk;
            *(uint2*)&act_t[cb] = pk;
        }
        {   // wl = 1
            const unsigned short q0 = f2bf(tanh_fast(a1h[0] + a1l[0] + biasr[1][0] + winr[1][0] * xv));
            const unsigned short q1 = f2bf(tanh_fast(a1h[1] + a1l[1] + biasr[1][1] + winr[1][1] * xv));
            const unsigned short q2 = f2bf(tanh_fast(a1h[2] + a1l[2] + biasr[1][2] + winr[1][2] * xv));
            const unsigned short q3 = f2bf(tanh_fast(a1h[3] + a1l[3] + biasr[1][3] + winr[1][3] * xv));
            uint2 pk;
            pk.x = (unsigned int)q0 | ((unsigned int)q1 << 16);
            pk.y = (unsigned int)q2 | ((unsigned int)q3 << 16);
            const int cb = wp * 32 + 16 + g * 4;
            *(uint2*)&wr[cb] = pk;
            *(uint2*)&act_t[cb] = pk;
        }
        __syncthreads();   // new h visible before next step's reads
    }

    // persist h-state (loop ended with a barrier -> safe to read)
    {
        const int r = tid >> 3, ch = (tid & 7) * 8;
        *(uint4*)&hstate[(size_t)bd * 2048 + r * 64 + ch] =
            *(const uint4*)&h_lds[(r + 1) * HLDS_STR + ch];
    }
}

// FC partials: one block per (tt, d, q4). acts layout is [tt][bd][r*64+o]:
// element e = oc*128 + j  ->  r = oc*2 + (j>>6), o = j&63.
__global__ __launch_bounds__(256, 2) void k_fc(
    const __hip_bfloat16* __restrict__ acts,
    const float* __restrict__ w_fc,
    float* __restrict__ partial,
    int t0)
{
    __shared__ unsigned short a_s[128 * ASTR];
    __shared__ float w_s[10 * 130];
    __shared__ float red[4 * 128 * 10];

    const int tid = threadIdx.x;
    const int blk = blockIdx.x;
    const int q4  = blk & 3;
    const int sub = blk >> 2;
    const int tt  = sub >> 2;
    const int d   = sub & 3;
    const int t   = t0 + tt;

    const int bloc = tid & 63;
    const int q = tid >> 6;

    float acc0[10], acc1[10];
    #pragma unroll
    for (int nn = 0; nn < 10; ++nn) { acc0[nn] = 0.0f; acc1[nn] = 0.0f; }

    const unsigned short* abase =
        (const unsigned short*)acts + ((size_t)tt * NBD + (size_t)d * 128) * 2048;

    for (int oc = q4 * 4; oc < q4 * 4 + 4; ++oc) {
        __syncthreads();
        #pragma unroll
        for (int it = 0; it < 8; ++it) {
            const int e = (it * 256 + tid) * 8;
            const int bb = e >> 7, j = e & 127;
            const uint4 v = *(const uint4*)(abase + (size_t)bb * 2048 + oc * 128 + j);
            unsigned int* dst = (unsigned int*)&a_s[bb * ASTR + j];
            dst[0] = v.x; dst[1] = v.y; dst[2] = v.z; dst[3] = v.w;
        }
        if (tid < 128) {
            const int j = tid;
            const int r = oc * 2 + (j >> 6);
            const int o = j & 63;
            const int c = t - r;
            const bool valid = (c >= 0) && (c < 32);
            const size_t row = ((size_t)(d * 64 + o) << 10) + (size_t)(r << 5) + (valid ? c : 0);
            #pragma unroll
            for (int nn = 0; nn < 10; ++nn)
                w_s[nn * 130 + j] = valid ? w_fc[row * 10 + nn] : 0.0f;
        }
        __syncthreads();
        #pragma unroll 4
        for (int jj = 0; jj < 32; jj += 2) {
            const int j = q * 32 + jj;
            const unsigned int va = *(const unsigned int*)&a_s[bloc * ASTR + j];
            const unsigned int vb = *(const unsigned int*)&a_s[(bloc + 64) * ASTR + j];
            const float a00 = bf2f(va & 0xffffu), a01 = bf2f(va >> 16);
            const float a10 = bf2f(vb & 0xffffu), a11 = bf2f(vb >> 16);
            #pragma unroll
            for (int nn = 0; nn < 10; ++nn) {
                const float2 wv = *(const float2*)&w_s[nn * 130 + j];
                acc0[nn] += a00 * wv.x + a01 * wv.y;
                acc1[nn] += a10 * wv.x + a11 * wv.y;
            }
        }
    }
    __syncthreads();
    #pragma unroll
    for (int nn = 0; nn < 10; ++nn) {
        red[(q * 128 + bloc) * 10 + nn]      = acc0[nn];
        red[(q * 128 + bloc + 64) * 10 + nn] = acc1[nn];
    }
    __syncthreads();
    for (int m = tid; m < 1280; m += 256) {
        const int bb = m / 10, nn = m % 10;
        const float sum = red[bb * 10 + nn] + red[(128 + bb) * 10 + nn]
                        + red[(256 + bb) * 10 + nn] + red[(384 + bb) * 10 + nn];
        partial[((size_t)(t * 4 + d) * 4 + q4) * 1280 + m] = sum;
    }
}

// Final reduce over 1008 partial slots + bias + log_softmax.
__global__ __launch_bounds__(256) void k_red(
    const float* __restrict__ partial,
    const float* __restrict__ b_fc,
    float* __restrict__ out)
{
    __shared__ float red2[250];
    __shared__ float lgs[10];
    __shared__ float lse;
    const int b = blockIdx.x;
    const int tid = threadIdx.x;
    if (tid < 250) {
        const int cs = tid / 10, nn = tid % 10;
        float acc = 0.0f;
        for (int c = cs; c < 1008; c += 25)
            acc += partial[(size_t)c * 1280 + b * 10 + nn];
        red2[tid] = acc;
    }
    __syncthreads();
    if (tid < 10) {
        float s = b_fc[tid];
        #pragma unroll
        for (int cs = 0; cs < 25; ++cs) s += red2[cs * 10 + tid];
        lgs[tid] = s;
    }
    __syncthreads();
    if (tid == 0) {
        float m = lgs[0];
        for (int nn = 1; nn < 10; ++nn) m = fmaxf(m, lgs[nn]);
        float ssum = 0.0f;
        for (int nn = 0; nn < 10; ++nn) ssum += __expf(lgs[nn] - m);
        lse = m + __logf(ssum);
    }
    __syncthreads();
    if (tid < 10) out[b * 10 + tid] = lgs[tid] - lse;
}

extern "C" void kernel_launch(void* const* d_in, const int* in_sizes, int n_in,
                              void* d_out, int out_size, void* d_ws, size_t ws_size,
                              hipStream_t stream)
{
    const float* x       = (const float*)d_in[0];
    const float* w_in    = (const float*)d_in[1];
    const float* b_in    = (const float*)d_in[2];
    const float* w_state = (const float*)d_in[3];
    const float* b_state = (const float*)d_in[4];
    const float* w_fc    = (const float*)d_in[5];
    const float* b_fc    = (const float*)d_in[6];
    float* out = (float*)d_out;

    const size_t HSTATE_BYTES  = (size_t)NBD * 2048 * 2;     // bf16 h-state
    const size_t PARTIAL_BYTES = (size_t)1008 * 1280 * 4;
    unsigned short* hstate = (unsigned short*)d_ws;
    float* partial = (float*)((char*)d_ws + HSTATE_BYTES);
    __hip_bfloat16* acts = (__hip_bfloat16*)((char*)d_ws + HSTATE_BYTES + PARTIAL_BYTES);

    const int tch_opts[4] = {63, 9, 3, 1};
    int tch = 1;
    for (int i = 0; i < 4; ++i) {
        const size_t need = HSTATE_BYTES + PARTIAL_BYTES
                          + (size_t)tch_opts[i] * NBD * 2048 * 2;
        if (ws_size >= need) { tch = tch_opts[i]; break; }
    }
    const int nch = NT / tch;

    for (int c = 0; c < nch; ++c) {
        k_rnn<<<512, 256, 0, stream>>>(x, w_in, b_in, w_state, b_state,
                                       acts, hstate, c * tch, tch);
        k_fc <<<tch * 16, 256, 0, stream>>>(acts, w_fc, partial, c * tch);
    }
    k_red<<<128, 256, 0, stream>>>(partial, b_fc, out);
}

// Round 4
// 100.103 us; speedup vs baseline: 5.2284x; 1.3399x over previous
//
#include <hip/hip_runtime.h>
#include <hip/hip_bf16.h>

#define NHID 64
#define NT   63
#define NBD  512
#define HLDS_STR 72   // shorts per h row (144 B): quarter-wave b128 reads 2-way (free)
#define XSTR 35       // floats per xs row
#define ASTR 130      // FC a-tile LDS stride (bf16 elems)

typedef __attribute__((ext_vector_type(8))) short bf16x8;
typedef __attribute__((ext_vector_type(4))) float f32x4;

__device__ __forceinline__ float tanh_fast(float x) {
    // 1 - 2/(e^{2x}+1): exact for +-large x (exp->inf => 1; exp->0 => -1)
    const float e = __expf(2.0f * x);
    const float r = __builtin_amdgcn_rcpf(e + 1.0f);
    return 1.0f - 2.0f * r;
}

__device__ __forceinline__ unsigned int cvt_pk_bf16(float lo, float hi) {
    unsigned int r;
    asm("v_cvt_pk_bf16_f32 %0, %1, %2" : "=v"(r) : "v"(lo), "v"(hi));
    return r;   // lo16 = bf16(lo), hi16 = bf16(hi), RNE
}

__device__ __forceinline__ float bf2f(unsigned int u16) {
    return __uint_as_float(u16 << 16);
}

// raw barrier: waits LDS ops only — global stores stay in flight (no vmcnt drain)
#define LGKM_BARRIER() do {                                   \
    asm volatile("s_waitcnt lgkmcnt(0)" ::: "memory");        \
    __builtin_amdgcn_s_barrier();                             \
    asm volatile("" ::: "memory");                            \
} while (0)

// MFMA recurrence: 1 block = 1 (dir,batch); 4 waves = (o-half) x (r-half).
// Double-buffered h in LDS (1 barrier/step, lgkm-only). Acts stored via the
// published h buffer as one coalesced uint4/thread (4 KB/block/step).
__global__ __launch_bounds__(256, 2) void k_rnn(
    const float* __restrict__ x,
    const float* __restrict__ w_in,
    const float* __restrict__ b_in,
    const float* __restrict__ w_state,
    const float* __restrict__ b_state,
    __hip_bfloat16* __restrict__ acts,
    unsigned short* __restrict__ hstate,
    int t0, int tch)
{
    __shared__ __align__(16) unsigned short h0buf[33 * HLDS_STR];
    __shared__ __align__(16) unsigned short h1buf[33 * HLDS_STR];
    __shared__ float xs[32 * XSTR];

    const int tid = threadIdx.x;
    const int bd  = blockIdx.x;
    const int d   = bd >> 7;
    const int b   = bd & 127;
    const int lane = tid & 63;
    const int wave = tid >> 6;
    const int wp = wave & 1;     // o-half
    const int nt = wave >> 1;    // r-half
    const int n  = lane & 15;
    const int g  = lane >> 4;

    // ---- stage x with direction flips ----
    const bool flr = (d & 1) != 0;
    const bool flc = (d & 2) != 0;
    const float* xb = x + (size_t)b * 1024;
    for (int idx = tid; idx < 1024; idx += 256) {
        const int r = idx >> 5, c = idx & 31;
        xs[r * XSTR + c] = xb[(flr ? 31 - r : r) * 32 + (flc ? 31 - c : c)];
    }

    // ---- zero both h buffers, then restore state into h0 ----
    for (int m2 = tid; m2 < (33 * HLDS_STR) / 2; m2 += 256) {
        ((unsigned int*)h0buf)[m2] = 0u;
        ((unsigned int*)h1buf)[m2] = 0u;
    }
    __syncthreads();
    if (t0 > 0) {
        const unsigned short* hs = hstate + (size_t)bd * 2048;
        const int r = tid >> 3, ch = (tid & 7) * 8;
        *(uint4*)&h0buf[(r + 1) * HLDS_STR + ch] = *(const uint4*)&hs[r * 64 + ch];
    }

    // ---- A fragments (weights), hi/lo bf16 split, loaded once ----
    bf16x8 a_hi[2][4], a_lo[2][4];
    #pragma unroll
    for (int wl = 0; wl < 2; ++wl) {
        const int o = wp * 32 + wl * 16 + n;
        #pragma unroll
        for (int kt = 0; kt < 4; ++kt) {
            const int s  = kt >> 1;
            const int cb = (kt & 1) * 32 + g * 8;
            bf16x8 hi8, lo8;
            #pragma unroll
            for (int j = 0; j < 8; ++j) {
                const float w = w_state[((size_t)o * 64 + cb + j) * 2 + s];
                const unsigned int hp = cvt_pk_bf16(w, 0.0f);
                const float wh = bf2f(hp & 0xffffu);
                const unsigned int lp = cvt_pk_bf16(w - wh, 0.0f);
                hi8[j] = (short)(hp & 0xffffu);
                lo8[j] = (short)(lp & 0xffffu);
            }
            a_hi[wl][kt] = hi8;
            a_lo[wl][kt] = lo8;
        }
    }

    float biasr[2][4], winr[2][4];
    #pragma unroll
    for (int wl = 0; wl < 2; ++wl)
        #pragma unroll
        for (int j = 0; j < 4; ++j) {
            const int o = wp * 32 + wl * 16 + g * 4 + j;
            biasr[wl][j] = b_in[o] + b_state[o];
            winr[wl][j]  = w_in[o];
        }

    const int r_out = nt * 16 + n;
    const int rdoff = r_out * HLDS_STR + g * 8;        // B-frag base (h[r-1] row)
    const int wroff = (r_out + 1) * HLDS_STR;          // h write row
    const int cb0 = wp * 32 + g * 4;
    unsigned short* act_base = (unsigned short*)acts + (size_t)bd * 2048;
    const int sr = (tid >> 3) + 1, sc = (tid & 7) * 8; // acts flush coords

    __syncthreads();

#define STEP(TT, RB, WB) do {                                                   \
    const int t_ = t0 + (TT);                                                   \
    const bf16x8 b0 = *(const bf16x8*)&RB[rdoff];                               \
    const bf16x8 b1 = *(const bf16x8*)&RB[rdoff + 32];                          \
    const bf16x8 b2 = *(const bf16x8*)&RB[rdoff + HLDS_STR];                    \
    const bf16x8 b3 = *(const bf16x8*)&RB[rdoff + HLDS_STR + 32];               \
    f32x4 a0h = {0,0,0,0}, a0l = {0,0,0,0}, a1h = {0,0,0,0}, a1l = {0,0,0,0};   \
    a0h = __builtin_amdgcn_mfma_f32_16x16x32_bf16(a_hi[0][0], b0, a0h, 0,0,0);  \
    a1h = __builtin_amdgcn_mfma_f32_16x16x32_bf16(a_hi[1][0], b0, a1h, 0,0,0);  \
    a0l = __builtin_amdgcn_mfma_f32_16x16x32_bf16(a_lo[0][0], b0, a0l, 0,0,0);  \
    a1l = __builtin_amdgcn_mfma_f32_16x16x32_bf16(a_lo[1][0], b0, a1l, 0,0,0);  \
    a0h = __builtin_amdgcn_mfma_f32_16x16x32_bf16(a_hi[0][1], b1, a0h, 0,0,0);  \
    a1h = __builtin_amdgcn_mfma_f32_16x16x32_bf16(a_hi[1][1], b1, a1h, 0,0,0);  \
    a0l = __builtin_amdgcn_mfma_f32_16x16x32_bf16(a_lo[0][1], b1, a0l, 0,0,0);  \
    a1l = __builtin_amdgcn_mfma_f32_16x16x32_bf16(a_lo[1][1], b1, a1l, 0,0,0);  \
    a0h = __builtin_amdgcn_mfma_f32_16x16x32_bf16(a_hi[0][2], b2, a0h, 0,0,0);  \
    a1h = __builtin_amdgcn_mfma_f32_16x16x32_bf16(a_hi[1][2], b2, a1h, 0,0,0);  \
    a0l = __builtin_amdgcn_mfma_f32_16x16x32_bf16(a_lo[0][2], b2, a0l, 0,0,0);  \
    a1l = __builtin_amdgcn_mfma_f32_16x16x32_bf16(a_lo[1][2], b2, a1l, 0,0,0);  \
    a0h = __builtin_amdgcn_mfma_f32_16x16x32_bf16(a_hi[0][3], b3, a0h, 0,0,0);  \
    a1h = __builtin_amdgcn_mfma_f32_16x16x32_bf16(a_hi[1][3], b3, a1h, 0,0,0);  \
    a0l = __builtin_amdgcn_mfma_f32_16x16x32_bf16(a_lo[0][3], b3, a0l, 0,0,0);  \
    a1l = __builtin_amdgcn_mfma_f32_16x16x32_bf16(a_lo[1][3], b3, a1l, 0,0,0);  \
    const int c_ = t_ - r_out;                                                  \
    const float xv = (c_ >= 0 && c_ < 32) ? xs[r_out * XSTR + c_] : 0.0f;       \
    {                                                                           \
        const float h0 = tanh_fast(a0h[0] + a0l[0] + biasr[0][0] + winr[0][0] * xv); \
        const float h1 = tanh_fast(a0h[1] + a0l[1] + biasr[0][1] + winr[0][1] * xv); \
        const float h2 = tanh_fast(a0h[2] + a0l[2] + biasr[0][2] + winr[0][2] * xv); \
        const float h3 = tanh_fast(a0h[3] + a0l[3] + biasr[0][3] + winr[0][3] * xv); \
        uint2 pk; pk.x = cvt_pk_bf16(h0, h1); pk.y = cvt_pk_bf16(h2, h3);       \
        *(uint2*)&WB[wroff + cb0] = pk;                                         \
    }                                                                           \
    {                                                                           \
        const float h0 = tanh_fast(a1h[0] + a1l[0] + biasr[1][0] + winr[1][0] * xv); \
        const float h1 = tanh_fast(a1h[1] + a1l[1] + biasr[1][1] + winr[1][1] * xv); \
        const float h2 = tanh_fast(a1h[2] + a1l[2] + biasr[1][2] + winr[1][2] * xv); \
        const float h3 = tanh_fast(a1h[3] + a1l[3] + biasr[1][3] + winr[1][3] * xv); \
        uint2 pk; pk.x = cvt_pk_bf16(h0, h1); pk.y = cvt_pk_bf16(h2, h3);       \
        *(uint2*)&WB[wroff + cb0 + 16] = pk;                                    \
    }                                                                           \
    LGKM_BARRIER();                                                             \
    const uint4 av = *(const uint4*)&WB[sr * HLDS_STR + sc];                    \
    *(uint4*)(act_base + (size_t)(TT) * NBD * 2048 + tid * 8) = av;             \
} while (0)

    int tt = 0;
    while (tt + 2 <= tch) {
        STEP(tt,     h0buf, h1buf);
        STEP(tt + 1, h1buf, h0buf);
        tt += 2;
    }
    if (tt < tch) STEP(tt, h0buf, h1buf);
#undef STEP

    // persist h-state (each STEP ends with a barrier; writes are visible)
    {
        const unsigned short* fin = (tch & 1) ? h1buf : h0buf;
        const int r = tid >> 3, ch = (tid & 7) * 8;
        *(uint4*)&hstate[(size_t)bd * 2048 + r * 64 + ch] =
            *(const uint4*)&fin[(r + 1) * HLDS_STR + ch];
    }
}

// FC partials: one block per (tt, d, q4). acts layout [tt][bd][r*64+o]:
// element e = oc*128 + j -> r = oc*2 + (j>>6), o = j&63.
__global__ __launch_bounds__(256, 2) void k_fc(
    const __hip_bfloat16* __restrict__ acts,
    const float* __restrict__ w_fc,
    float* __restrict__ partial,
    int t0)
{
    __shared__ unsigned short a_s[128 * ASTR];
    __shared__ float w_s[10 * 130];
    __shared__ float red[4 * 128 * 10];

    const int tid = threadIdx.x;
    const int blk = blockIdx.x;
    const int q4  = blk & 3;
    const int sub = blk >> 2;
    const int tt  = sub >> 2;
    const int d   = sub & 3;
    const int t   = t0 + tt;

    const int bloc = tid & 63;
    const int q = tid >> 6;

    float acc0[10], acc1[10];
    #pragma unroll
    for (int nn = 0; nn < 10; ++nn) { acc0[nn] = 0.0f; acc1[nn] = 0.0f; }

    const unsigned short* abase =
        (const unsigned short*)acts + ((size_t)tt * NBD + (size_t)d * 128) * 2048;

    for (int oc = q4 * 4; oc < q4 * 4 + 4; ++oc) {
        __syncthreads();
        #pragma unroll
        for (int it = 0; it < 8; ++it) {
            const int e = (it * 256 + tid) * 8;
            const int bb = e >> 7, j = e & 127;
            const uint4 v = *(const uint4*)(abase + (size_t)bb * 2048 + oc * 128 + j);
            unsigned int* dst = (unsigned int*)&a_s[bb * ASTR + j];
            dst[0] = v.x; dst[1] = v.y; dst[2] = v.z; dst[3] = v.w;
        }
        if (tid < 128) {
            const int j = tid;
            const int r = oc * 2 + (j >> 6);
            const int o = j & 63;
            const int c = t - r;
            const bool valid = (c >= 0) && (c < 32);
            const size_t row = ((size_t)(d * 64 + o) << 10) + (size_t)(r << 5) + (valid ? c : 0);
            #pragma unroll
            for (int nn = 0; nn < 10; ++nn)
                w_s[nn * 130 + j] = valid ? w_fc[row * 10 + nn] : 0.0f;
        }
        __syncthreads();
        #pragma unroll 4
        for (int jj = 0; jj < 32; jj += 2) {
            const int j = q * 32 + jj;
            const unsigned int va = *(const unsigned int*)&a_s[bloc * ASTR + j];
            const unsigned int vb = *(const unsigned int*)&a_s[(bloc + 64) * ASTR + j];
            const float a00 = bf2f(va & 0xffffu), a01 = bf2f(va >> 16);
            const float a10 = bf2f(vb & 0xffffu), a11 = bf2f(vb >> 16);
            #pragma unroll
            for (int nn = 0; nn < 10; ++nn) {
                const float2 wv = *(const float2*)&w_s[nn * 130 + j];
                acc0[nn] += a00 * wv.x + a01 * wv.y;
                acc1[nn] += a10 * wv.x + a11 * wv.y;
            }
        }
    }
    __syncthreads();
    #pragma unroll
    for (int nn = 0; nn < 10; ++nn) {
        red[(q * 128 + bloc) * 10 + nn]      = acc0[nn];
        red[(q * 128 + bloc + 64) * 10 + nn] = acc1[nn];
    }
    __syncthreads();
    for (int m = tid; m < 1280; m += 256) {
        const int bb = m / 10, nn = m % 10;
        const float sum = red[bb * 10 + nn] + red[(128 + bb) * 10 + nn]
                        + red[(256 + bb) * 10 + nn] + red[(384 + bb) * 10 + nn];
        partial[((size_t)(t * 4 + d) * 4 + q4) * 1280 + m] = sum;
    }
}

// Stage A: coalesced reduction of 1008 slots -> 63. Block k sums 16 slots.
__global__ __launch_bounds__(256) void k_redA(
    const float* __restrict__ partial,
    float* __restrict__ stage1)
{
    const int k = blockIdx.x;           // 0..62
    const int tid = threadIdx.x;
    for (int e = tid; e < 1280; e += 256) {
        float acc = 0.0f;
        #pragma unroll
        for (int s = 0; s < 16; ++s)
            acc += partial[(size_t)(k * 16 + s) * 1280 + e];
        stage1[(size_t)k * 1280 + e] = acc;
    }
}

// Stage B: sum 63 -> logits, bias, log_softmax. One block per batch row.
__global__ __launch_bounds__(256) void k_redB(
    const float* __restrict__ stage1,
    const float* __restrict__ b_fc,
    float* __restrict__ out)
{
    __shared__ float red[630];
    __shared__ float lgs[10];
    __shared__ float lse;
    const int b = blockIdx.x;
    const int tid = threadIdx.x;
    for (int m = tid; m < 630; m += 256) {
        const int k = m / 10, nn = m % 10;
        red[m] = stage1[(size_t)k * 1280 + b * 10 + nn];
    }
    __syncthreads();
    if (tid < 10) {
        float s = b_fc[tid];
        for (int k = 0; k < 63; ++k) s += red[k * 10 + tid];
        lgs[tid] = s;
    }
    __syncthreads();
    if (tid == 0) {
        float m = lgs[0];
        for (int nn = 1; nn < 10; ++nn) m = fmaxf(m, lgs[nn]);
        float ssum = 0.0f;
        for (int nn = 0; nn < 10; ++nn) ssum += __expf(lgs[nn] - m);
        lse = m + __logf(ssum);
    }
    __syncthreads();
    if (tid < 10) out[b * 10 + tid] = lgs[tid] - lse;
}

extern "C" void kernel_launch(void* const* d_in, const int* in_sizes, int n_in,
                              void* d_out, int out_size, void* d_ws, size_t ws_size,
                              hipStream_t stream)
{
    const float* x       = (const float*)d_in[0];
    const float* w_in    = (const float*)d_in[1];
    const float* b_in    = (const float*)d_in[2];
    const float* w_state = (const float*)d_in[3];
    const float* b_state = (const float*)d_in[4];
    const float* w_fc    = (const float*)d_in[5];
    const float* b_fc    = (const float*)d_in[6];
    float* out = (float*)d_out;

    const size_t HSTATE_BYTES  = (size_t)NBD * 2048 * 2;     // bf16 h-state
    const size_t PARTIAL_BYTES = (size_t)1008 * 1280 * 4;
    const size_t STAGE1_BYTES  = (size_t)63 * 1280 * 4;
    unsigned short* hstate = (unsigned short*)d_ws;
    float* partial = (float*)((char*)d_ws + HSTATE_BYTES);
    float* stage1  = (float*)((char*)d_ws + HSTATE_BYTES + PARTIAL_BYTES);
    __hip_bfloat16* acts = (__hip_bfloat16*)((char*)d_ws + HSTATE_BYTES
                                             + PARTIAL_BYTES + STAGE1_BYTES);

    const int tch_opts[4] = {63, 9, 3, 1};
    int tch = 1;
    for (int i = 0; i < 4; ++i) {
        const size_t need = HSTATE_BYTES + PARTIAL_BYTES + STAGE1_BYTES
                          + (size_t)tch_opts[i] * NBD * 2048 * 2;
        if (ws_size >= need) { tch = tch_opts[i]; break; }
    }
    const int nch = NT / tch;

    for (int c = 0; c < nch; ++c) {
        k_rnn<<<512, 256, 0, stream>>>(x, w_in, b_in, w_state, b_state,
                                       acts, hstate, c * tch, tch);
        k_fc <<<tch * 16, 256, 0, stream>>>(acts, w_fc, partial, c * tch);
    }
    k_redA<<<63, 256, 0, stream>>>(partial, stage1);
    k_redB<<<128, 256, 0, stream>>>(stage1, b_fc, out);
}

// Round 5
// 78.803 us; speedup vs baseline: 6.6416x; 1.2703x over previous
//
#include <hip/hip_runtime.h>
#include <hip/hip_bf16.h>

#define NHID 64
#define NT   63
#define NBD  512
#define HLDS_STR 72   // shorts per h row (144 B): quarter-wave b128 reads 2-way (free)
#define XSTR 35       // floats per xs row

typedef __attribute__((ext_vector_type(8))) short bf16x8;
typedef __attribute__((ext_vector_type(4))) float f32x4;

__device__ __forceinline__ float tanh_fast(float x) {
    // 1 - 2/(e^{2x}+1): exact for +-large x (exp->inf => 1; exp->0 => -1)
    const float e = __expf(2.0f * x);
    const float r = __builtin_amdgcn_rcpf(e + 1.0f);
    return 1.0f - 2.0f * r;
}

__device__ __forceinline__ unsigned int cvt_pk_bf16(float lo, float hi) {
    unsigned int r;
    asm("v_cvt_pk_bf16_f32 %0, %1, %2" : "=v"(r) : "v"(lo), "v"(hi));
    return r;   // lo16 = bf16(lo), hi16 = bf16(hi), RNE
}

__device__ __forceinline__ float bf2f(unsigned int u16) {
    return __uint_as_float(u16 << 16);
}

// skew-diagonal geometry: valid rows r in [r0(t), r1(t)], compact prefix off(t)
#define SKEW_R0(t)  ((t) > 31 ? (t) - 31 : 0)
#define SKEW_R1(t)  ((t) < 31 ? (t) : 31)
#define SKEW_OFF(t) ((t) < 32 ? ((t) * ((t) + 1)) >> 1 : 1024 - (((63 - (t)) * (64 - (t))) >> 1))

// raw barrier: waits LDS ops only — global stores stay in flight (no vmcnt drain)
#define LGKM_BARRIER() do {                                   \
    asm volatile("s_waitcnt lgkmcnt(0)" ::: "memory");        \
    __builtin_amdgcn_s_barrier();                             \
    asm volatile("" ::: "memory");                            \
} while (0)

// ---------------------------------------------------------------------------
// k_rnn: 1 block = 1 (dir,batch); 4 waves = (o-half) x (r-half). Double-buffered
// h in LDS, 1 lgkm-only barrier/step. Stores ONLY valid skew cells, compact:
// acts_c[(off(t) + r-r0)*... ] layout [t][bd][(r-r0)*64+o], 67 MB total.
// ---------------------------------------------------------------------------
__global__ __launch_bounds__(256, 2) void k_rnn(
    const float* __restrict__ x,
    const float* __restrict__ w_in,
    const float* __restrict__ b_in,
    const float* __restrict__ w_state,
    const float* __restrict__ b_state,
    unsigned short* __restrict__ acts_c)
{
    __shared__ __align__(16) unsigned short h0buf[33 * HLDS_STR];
    __shared__ __align__(16) unsigned short h1buf[33 * HLDS_STR];
    __shared__ float xs[32 * XSTR];

    const int tid = threadIdx.x;
    const int bd  = blockIdx.x;
    const int d   = bd >> 7;
    const int b   = bd & 127;
    const int lane = tid & 63;
    const int wave = tid >> 6;
    const int wp = wave & 1;     // o-half
    const int nt = wave >> 1;    // r-half
    const int n  = lane & 15;
    const int g  = lane >> 4;

    // ---- stage x with direction flips ----
    const bool flr = (d & 1) != 0;
    const bool flc = (d & 2) != 0;
    const float* xb = x + (size_t)b * 1024;
    for (int idx = tid; idx < 1024; idx += 256) {
        const int r = idx >> 5, c = idx & 31;
        xs[r * XSTR + c] = xb[(flr ? 31 - r : r) * 32 + (flc ? 31 - c : c)];
    }

    // ---- zero both h buffers ----
    for (int m2 = tid; m2 < (33 * HLDS_STR) / 2; m2 += 256) {
        ((unsigned int*)h0buf)[m2] = 0u;
        ((unsigned int*)h1buf)[m2] = 0u;
    }

    // ---- A fragments (weights), hi/lo bf16 split, loaded once ----
    bf16x8 a_hi[2][4], a_lo[2][4];
    #pragma unroll
    for (int wl = 0; wl < 2; ++wl) {
        const int o = wp * 32 + wl * 16 + n;
        #pragma unroll
        for (int kt = 0; kt < 4; ++kt) {
            const int s  = kt >> 1;
            const int cb = (kt & 1) * 32 + g * 8;
            bf16x8 hi8, lo8;
            #pragma unroll
            for (int j = 0; j < 8; ++j) {
                const float w = w_state[((size_t)o * 64 + cb + j) * 2 + s];
                const unsigned int hp = cvt_pk_bf16(w, 0.0f);
                const float wh = bf2f(hp & 0xffffu);
                const unsigned int lp = cvt_pk_bf16(w - wh, 0.0f);
                hi8[j] = (short)(hp & 0xffffu);
                lo8[j] = (short)(lp & 0xffffu);
            }
            a_hi[wl][kt] = hi8;
            a_lo[wl][kt] = lo8;
        }
    }

    float biasr[2][4], winr[2][4];
    #pragma unroll
    for (int wl = 0; wl < 2; ++wl)
        #pragma unroll
        for (int j = 0; j < 4; ++j) {
            const int o = wp * 32 + wl * 16 + g * 4 + j;
            biasr[wl][j] = b_in[o] + b_state[o];
            winr[wl][j]  = w_in[o];
        }

    const int r_out = nt * 16 + n;
    const int rdoff = r_out * HLDS_STR + g * 8;        // B-frag base (h[r-1] row)
    const int wroff = (r_out + 1) * HLDS_STR;          // h write row
    const int cb0 = wp * 32 + g * 4;
    const int sr = (tid >> 3) + 1, sc = (tid & 7) * 8; // flush coords
    const int rr = tid >> 3;                            // flush r

    __syncthreads();

#define STEP(TT, RB, WB) do {                                                   \
    const int t_ = (TT);                                                        \
    const bf16x8 b0 = *(const bf16x8*)&RB[rdoff];                               \
    const bf16x8 b1 = *(const bf16x8*)&RB[rdoff + 32];                          \
    const bf16x8 b2 = *(const bf16x8*)&RB[rdoff + HLDS_STR];                    \
    const bf16x8 b3 = *(const bf16x8*)&RB[rdoff + HLDS_STR + 32];               \
    f32x4 a0h = {0,0,0,0}, a0l = {0,0,0,0}, a1h = {0,0,0,0}, a1l = {0,0,0,0};   \
    a0h = __builtin_amdgcn_mfma_f32_16x16x32_bf16(a_hi[0][0], b0, a0h, 0,0,0);  \
    a1h = __builtin_amdgcn_mfma_f32_16x16x32_bf16(a_hi[1][0], b0, a1h, 0,0,0);  \
    a0l = __builtin_amdgcn_mfma_f32_16x16x32_bf16(a_lo[0][0], b0, a0l, 0,0,0);  \
    a1l = __builtin_amdgcn_mfma_f32_16x16x32_bf16(a_lo[1][0], b0, a1l, 0,0,0);  \
    a0h = __builtin_amdgcn_mfma_f32_16x16x32_bf16(a_hi[0][1], b1, a0h, 0,0,0);  \
    a1h = __builtin_amdgcn_mfma_f32_16x16x32_bf16(a_hi[1][1], b1, a1h, 0,0,0);  \
    a0l = __builtin_amdgcn_mfma_f32_16x16x32_bf16(a_lo[0][1], b1, a0l, 0,0,0);  \
    a1l = __builtin_amdgcn_mfma_f32_16x16x32_bf16(a_lo[1][1], b1, a1l, 0,0,0);  \
    a0h = __builtin_amdgcn_mfma_f32_16x16x32_bf16(a_hi[0][2], b2, a0h, 0,0,0);  \
    a1h = __builtin_amdgcn_mfma_f32_16x16x32_bf16(a_hi[1][2], b2, a1h, 0,0,0);  \
    a0l = __builtin_amdgcn_mfma_f32_16x16x32_bf16(a_lo[0][2], b2, a0l, 0,0,0);  \
    a1l = __builtin_amdgcn_mfma_f32_16x16x32_bf16(a_lo[1][2], b2, a1l, 0,0,0);  \
    a0h = __builtin_amdgcn_mfma_f32_16x16x32_bf16(a_hi[0][3], b3, a0h, 0,0,0);  \
    a1h = __builtin_amdgcn_mfma_f32_16x16x32_bf16(a_hi[1][3], b3, a1h, 0,0,0);  \
    a0l = __builtin_amdgcn_mfma_f32_16x16x32_bf16(a_lo[0][3], b3, a0l, 0,0,0);  \
    a1l = __builtin_amdgcn_mfma_f32_16x16x32_bf16(a_lo[1][3], b3, a1l, 0,0,0);  \
    const int c_ = t_ - r_out;                                                  \
    const float xv = (c_ >= 0 && c_ < 32) ? xs[r_out * XSTR + c_] : 0.0f;       \
    {                                                                           \
        const float h0 = tanh_fast(a0h[0] + a0l[0] + biasr[0][0] + winr[0][0] * xv); \
        const float h1 = tanh_fast(a0h[1] + a0l[1] + biasr[0][1] + winr[0][1] * xv); \
        const float h2 = tanh_fast(a0h[2] + a0l[2] + biasr[0][2] + winr[0][2] * xv); \
        const float h3 = tanh_fast(a0h[3] + a0l[3] + biasr[0][3] + winr[0][3] * xv); \
        uint2 pk; pk.x = cvt_pk_bf16(h0, h1); pk.y = cvt_pk_bf16(h2, h3);       \
        *(uint2*)&WB[wroff + cb0] = pk;                                         \
    }                                                                           \
    {                                                                           \
        const float h0 = tanh_fast(a1h[0] + a1l[0] + biasr[1][0] + winr[1][0] * xv); \
        const float h1 = tanh_fast(a1h[1] + a1l[1] + biasr[1][1] + winr[1][1] * xv); \
        const float h2 = tanh_fast(a1h[2] + a1l[2] + biasr[1][2] + winr[1][2] * xv); \
        const float h3 = tanh_fast(a1h[3] + a1l[3] + biasr[1][3] + winr[1][3] * xv); \
        uint2 pk; pk.x = cvt_pk_bf16(h0, h1); pk.y = cvt_pk_bf16(h2, h3);       \
        *(uint2*)&WB[wroff + cb0 + 16] = pk;                                    \
    }                                                                           \
    LGKM_BARRIER();                                                             \
    const uint4 av = *(const uint4*)&WB[sr * HLDS_STR + sc];                    \
    const int r0_ = SKEW_R0(t_), r1_ = SKEW_R1(t_);                             \
    if (rr >= r0_ && rr <= r1_) {                                               \
        const int cnt_ = r1_ - r0_ + 1;                                         \
        const int off_ = SKEW_OFF(t_);                                          \
        *(uint4*)(acts_c + ((size_t)off_ * 512 + (size_t)bd * cnt_) * 64        \
                  + (((rr - r0_) * 8 + (tid & 7)) * 8)) = av;                   \
    }                                                                           \
} while (0)

    int tt = 0;
    while (tt + 2 <= NT) {
        STEP(tt,     h0buf, h1buf);
        STEP(tt + 1, h1buf, h0buf);
        tt += 2;
    }
    STEP(62, h0buf, h1buf);   // NT=63 odd: final step reads h0
#undef STEP
}

// ---------------------------------------------------------------------------
// k_prep: pre-swizzle w_fc into exact MFMA B-fragment order, bf16, skew-gated.
// Layout: [t]{ [d][ks][lane][j] }, base(t) = off(t)*4096 shorts.
// B[k][n] with k = ks*32 + (lane>>4)*8 + j, n = lane&15 (n>=10 -> 0).
// k indexes e = (r-r0)*64 + o;  w_fc row = ((d*64+o)<<10) + (r<<5) + (t-r).
// ---------------------------------------------------------------------------
__global__ __launch_bounds__(256) void k_prep(
    const float* __restrict__ w_fc,
    unsigned short* __restrict__ wt_swz)
{
    const int t = blockIdx.y;
    const int tid = threadIdx.x;
    const int r0 = SKEW_R0(t), r1 = SKEW_R1(t);
    const int cnt = r1 - r0 + 1;
    const int span = cnt << 10;                    // shorts per d
    int f = blockIdx.x * 2048 + tid * 8;           // short index within t-region
    const int fdst = f;
    if (f >= 4 * span) return;
    int d = 0;
    while (f >= span) { f -= span; ++d; }          // <=3 iters
    const int ks   = f >> 9;
    const int lane = (f >> 3) & 63;
    const int g = lane >> 4, n = lane & 15;
    unsigned int pk[4];
    #pragma unroll
    for (int jj = 0; jj < 4; ++jj) {
        float v[2] = {0.0f, 0.0f};
        #pragma unroll
        for (int h = 0; h < 2; ++h) {
            const int j = jj * 2 + h;
            const int k = ks * 32 + g * 8 + j;
            const int r = r0 + (k >> 6);
            const int o = k & 63;
            const int c = t - r;                   // guaranteed in [0,32)
            if (n < 10)
                v[h] = w_fc[((((size_t)(d * 64 + o)) << 10) + (r << 5) + c) * 10 + n];
        }
        pk[jj] = cvt_pk_bf16(v[0], v[1]);
    }
    uint4 st; st.x = pk[0]; st.y = pk[1]; st.z = pk[2]; st.w = pk[3];
    *(uint4*)(wt_swz + (size_t)SKEW_OFF(t) * 4096 + fdst) = st;
}

// ---------------------------------------------------------------------------
// k_fc: pure-streaming MFMA GEMM. Block = (t, d, mh); 4 waves = 4 M-tiles of
// 16 batches. Per K-step: A 16B/lane + B 16B/lane from global + 1 MFMA.
// Writes deterministic per-t partial[t][batch][16].
// ---------------------------------------------------------------------------
__global__ __launch_bounds__(256, 4) void k_fc(
    const unsigned short* __restrict__ acts_c,
    const unsigned short* __restrict__ wt_swz,
    float* __restrict__ partial)
{
    const int tid = threadIdx.x;
    const int blk = blockIdx.x;          // 63*8
    const int t   = blk >> 3;
    const int d   = (blk >> 1) & 3;
    const int mh  = blk & 1;
    const int lane = tid & 63;
    const int wv  = tid >> 6;
    const int g   = lane >> 4;
    const int n   = lane & 15;

    const int r0 = SKEW_R0(t), r1 = SKEW_R1(t);
    const int cnt = r1 - r0 + 1;
    const int off = SKEW_OFF(t);

    const int tb = d * 128 + mh * 64 + wv * 16;
    const unsigned short* Ab = acts_c
        + ((size_t)off * 512 + (size_t)(tb + n) * cnt) * 64 + g * 8;
    const unsigned short* Bb = wt_swz
        + ((size_t)off * 4 + (size_t)d * cnt) * 1024 + lane * 8;

    f32x4 acc = {0.f, 0.f, 0.f, 0.f};
    const int kmax = 2 * cnt;            // always even
    #pragma unroll 2
    for (int ks = 0; ks < kmax; ks += 2) {
        const bf16x8 a0 = *(const bf16x8*)(Ab + ks * 32);
        const bf16x8 bb0 = *(const bf16x8*)(Bb + (size_t)ks * 512);
        const bf16x8 a1 = *(const bf16x8*)(Ab + ks * 32 + 32);
        const bf16x8 bb1 = *(const bf16x8*)(Bb + (size_t)ks * 512 + 512);
        acc = __builtin_amdgcn_mfma_f32_16x16x32_bf16(a0, bb0, acc, 0, 0, 0);
        acc = __builtin_amdgcn_mfma_f32_16x16x32_bf16(a1, bb1, acc, 0, 0, 0);
    }
    const int batch = tb + g * 4;
    #pragma unroll
    for (int reg = 0; reg < 4; ++reg)
        partial[((size_t)t * 512 + batch + reg) * 16 + n] = acc[reg];
}

// ---------------------------------------------------------------------------
// k_out: per output batch b: logits[n] = b_fc[n] + sum_{t,d} partial; log_softmax.
// ---------------------------------------------------------------------------
__global__ __launch_bounds__(256) void k_out(
    const float* __restrict__ partial,
    const float* __restrict__ b_fc,
    float* __restrict__ out)
{
    __shared__ float lred[252 * 10];
    __shared__ float lgs[10];
    __shared__ float lse;
    const int b = blockIdx.x;
    const int tid = threadIdx.x;
    if (tid < 252) {
        const int t = tid >> 2, d = tid & 3;
        const float* p = partial + ((size_t)t * 512 + d * 128 + b) * 16;
        #pragma unroll
        for (int n2 = 0; n2 < 10; ++n2) lred[tid * 10 + n2] = p[n2];
    }
    __syncthreads();
    if (tid < 10) {
        float s = b_fc[tid];
        for (int i = 0; i < 252; ++i) s += lred[i * 10 + tid];
        lgs[tid] = s;
    }
    __syncthreads();
    if (tid == 0) {
        float m = lgs[0];
        for (int nn = 1; nn < 10; ++nn) m = fmaxf(m, lgs[nn]);
        float ssum = 0.0f;
        for (int nn = 0; nn < 10; ++nn) ssum += __expf(lgs[nn] - m);
        lse = m + __logf(ssum);
    }
    __syncthreads();
    if (tid < 10) out[b * 10 + tid] = lgs[tid] - lse;
}

extern "C" void kernel_launch(void* const* d_in, const int* in_sizes, int n_in,
                              void* d_out, int out_size, void* d_ws, size_t ws_size,
                              hipStream_t stream)
{
    const float* x       = (const float*)d_in[0];
    const float* w_in    = (const float*)d_in[1];
    const float* b_in    = (const float*)d_in[2];
    const float* w_state = (const float*)d_in[3];
    const float* b_state = (const float*)d_in[4];
    const float* w_fc    = (const float*)d_in[5];
    const float* b_fc    = (const float*)d_in[6];
    float* out = (float*)d_out;

    // ws layout: wt_swz 8 MiB | partial 2 MiB | acts_c 64 MiB  => 80 MiB total
    unsigned short* wt_swz = (unsigned short*)d_ws;
    float* partial = (float*)((char*)d_ws + (size_t)(8u << 20));
    unsigned short* acts_c = (unsigned short*)((char*)d_ws + (size_t)(16u << 20));

    k_prep<<<dim3(64, 63), 256, 0, stream>>>(w_fc, wt_swz);
    k_rnn <<<512, 256, 0, stream>>>(x, w_in, b_in, w_state, b_state, acts_c);
    k_fc  <<<504, 256, 0, stream>>>(acts_c, wt_swz, partial);
    k_out <<<128, 256, 0, stream>>>(partial, b_fc, out);
}

// Round 6
// 75.883 us; speedup vs baseline: 6.8972x; 1.0385x over previous
//
#include <hip/hip_runtime.h>
#include <hip/hip_bf16.h>

#define NHID 64
#define NT   63
#define NBD  512
#define HLDS_STR 72   // shorts per h row (144 B): quarter-wave b128 reads 2-way (free)
#define XSTR 35       // floats per xs row

typedef __attribute__((ext_vector_type(8))) short bf16x8;
typedef __attribute__((ext_vector_type(4))) float f32x4;

__device__ __forceinline__ float tanh_fast(float x) {
    // 1 - 2/(e^{2x}+1): exact for +-large x (exp->inf => 1; exp->0 => -1)
    const float e = __expf(2.0f * x);
    const float r = __builtin_amdgcn_rcpf(e + 1.0f);
    return 1.0f - 2.0f * r;
}

__device__ __forceinline__ unsigned int cvt_pk_bf16(float lo, float hi) {
    unsigned int r;
    asm("v_cvt_pk_bf16_f32 %0, %1, %2" : "=v"(r) : "v"(lo), "v"(hi));
    return r;   // lo16 = bf16(lo), hi16 = bf16(hi), RNE
}

__device__ __forceinline__ float bf2f(unsigned int u16) {
    return __uint_as_float(u16 << 16);
}

// skew-diagonal geometry (weights/k_fc only): valid rows r in [r0,r1], prefix off(t)
#define SKEW_R0(t)  ((t) > 31 ? (t) - 31 : 0)
#define SKEW_R1(t)  ((t) < 31 ? (t) : 31)
#define SKEW_OFF(t) ((t) < 32 ? ((t) * ((t) + 1)) >> 1 : 1024 - (((63 - (t)) * (64 - (t))) >> 1))

// raw barrier: waits LDS ops only — global stores stay in flight (no vmcnt drain)
#define LGKM_BARRIER() do {                                   \
    asm volatile("s_waitcnt lgkmcnt(0)" ::: "memory");        \
    __builtin_amdgcn_s_barrier();                             \
    asm volatile("" ::: "memory");                            \
} while (0)

// ---------------------------------------------------------------------------
// k_rnn: 1 block = 1 (dir,batch); 4 waves = (o-half wp) x (r-half nt).
// Double-buffered h in LDS, 1 lgkm-only barrier/step. Acts stored UNSKEWED
// [bd][r][c][o] (bf16, 64 MB): flush pointer advances +128 B/step (linear in
// t), validity = counter compare. No skew math inside the step loop.
// ---------------------------------------------------------------------------
__global__ __launch_bounds__(256, 2) void k_rnn(
    const float* __restrict__ x,
    const float* __restrict__ w_in,
    const float* __restrict__ b_in,
    const float* __restrict__ w_state,
    const float* __restrict__ b_state,
    unsigned short* __restrict__ acts_c)
{
    __shared__ __align__(16) unsigned short h0buf[33 * HLDS_STR];
    __shared__ __align__(16) unsigned short h1buf[33 * HLDS_STR];
    __shared__ float xs[32 * XSTR];

    const int tid = threadIdx.x;
    const int bd  = blockIdx.x;
    const int d   = bd >> 7;
    const int b   = bd & 127;
    const int lane = tid & 63;
    const int wave = tid >> 6;
    const int wp = wave & 1;     // o-half
    const int nt = wave >> 1;    // r-half
    const int n  = lane & 15;
    const int g  = lane >> 4;

    // ---- stage x with direction flips ----
    const bool flr = (d & 1) != 0;
    const bool flc = (d & 2) != 0;
    const float* xb = x + (size_t)b * 1024;
    for (int idx = tid; idx < 1024; idx += 256) {
        const int r = idx >> 5, c = idx & 31;
        xs[r * XSTR + c] = xb[(flr ? 31 - r : r) * 32 + (flc ? 31 - c : c)];
    }

    // ---- zero both h buffers ----
    for (int m2 = tid; m2 < (33 * HLDS_STR) / 2; m2 += 256) {
        ((unsigned int*)h0buf)[m2] = 0u;
        ((unsigned int*)h1buf)[m2] = 0u;
    }

    // ---- A fragments (weights), hi/lo bf16 split, loaded once ----
    bf16x8 a_hi[2][4], a_lo[2][4];
    #pragma unroll
    for (int wl = 0; wl < 2; ++wl) {
        const int o = wp * 32 + wl * 16 + n;
        #pragma unroll
        for (int kt = 0; kt < 4; ++kt) {
            const int s  = kt >> 1;
            const int cb = (kt & 1) * 32 + g * 8;
            bf16x8 hi8, lo8;
            #pragma unroll
            for (int j = 0; j < 8; ++j) {
                const float w = w_state[((size_t)o * 64 + cb + j) * 2 + s];
                const unsigned int hp = cvt_pk_bf16(w, 0.0f);
                const float wh = bf2f(hp & 0xffffu);
                const unsigned int lp = cvt_pk_bf16(w - wh, 0.0f);
                hi8[j] = (short)(hp & 0xffffu);
                lo8[j] = (short)(lp & 0xffffu);
            }
            a_hi[wl][kt] = hi8;
            a_lo[wl][kt] = lo8;
        }
    }

    float biasr[2][4], winr[2][4];
    #pragma unroll
    for (int wl = 0; wl < 2; ++wl)
        #pragma unroll
        for (int j = 0; j < 4; ++j) {
            const int o = wp * 32 + wl * 16 + g * 4 + j;
            biasr[wl][j] = b_in[o] + b_state[o];
            winr[wl][j]  = w_in[o];
        }

    const int r_out = nt * 16 + n;
    const int rdoff = r_out * HLDS_STR + g * 8;        // B-frag base (h[r-1] row)
    const int wroff = (r_out + 1) * HLDS_STR;          // h write row
    const int cb0 = wp * 32 + g * 4;
    const int r_f = tid >> 3;                          // flush row 0..31
    const int sc  = (tid & 7) * 8;                     // flush o-chunk
    const int fl_off = (r_f + 1) * HLDS_STR + sc;

    // unskewed acts: addr(t) = bd*65536 + r_f*2048 + (t-r_f)*64 + sc
    unsigned short* actp = acts_c + (size_t)bd * 65536 + (size_t)r_f * 1984 + sc;
    int cc  = -r_out;    // = t - r_out (xv gate)
    int ccf = -r_f;      // = t - r_f  (flush gate)
    const float* xs_r = &xs[r_out * XSTR];

    __syncthreads();

#define STEP(RB, WB) do {                                                       \
    const bf16x8 b0 = *(const bf16x8*)&RB[rdoff];                               \
    const bf16x8 b1 = *(const bf16x8*)&RB[rdoff + 32];                          \
    const bf16x8 b2 = *(const bf16x8*)&RB[rdoff + HLDS_STR];                    \
    const bf16x8 b3 = *(const bf16x8*)&RB[rdoff + HLDS_STR + 32];               \
    f32x4 a0h = {0,0,0,0}, a0l = {0,0,0,0}, a1h = {0,0,0,0}, a1l = {0,0,0,0};   \
    a0h = __builtin_amdgcn_mfma_f32_16x16x32_bf16(a_hi[0][0], b0, a0h, 0,0,0);  \
    a1h = __builtin_amdgcn_mfma_f32_16x16x32_bf16(a_hi[1][0], b0, a1h, 0,0,0);  \
    a0l = __builtin_amdgcn_mfma_f32_16x16x32_bf16(a_lo[0][0], b0, a0l, 0,0,0);  \
    a1l = __builtin_amdgcn_mfma_f32_16x16x32_bf16(a_lo[1][0], b0, a1l, 0,0,0);  \
    a0h = __builtin_amdgcn_mfma_f32_16x16x32_bf16(a_hi[0][1], b1, a0h, 0,0,0);  \
    a1h = __builtin_amdgcn_mfma_f32_16x16x32_bf16(a_hi[1][1], b1, a1h, 0,0,0);  \
    a0l = __builtin_amdgcn_mfma_f32_16x16x32_bf16(a_lo[0][1], b1, a0l, 0,0,0);  \
    a1l = __builtin_amdgcn_mfma_f32_16x16x32_bf16(a_lo[1][1], b1, a1l, 0,0,0);  \
    a0h = __builtin_amdgcn_mfma_f32_16x16x32_bf16(a_hi[0][2], b2, a0h, 0,0,0);  \
    a1h = __builtin_amdgcn_mfma_f32_16x16x32_bf16(a_hi[1][2], b2, a1h, 0,0,0);  \
    a0l = __builtin_amdgcn_mfma_f32_16x16x32_bf16(a_lo[0][2], b2, a0l, 0,0,0);  \
    a1l = __builtin_amdgcn_mfma_f32_16x16x32_bf16(a_lo[1][2], b2, a1l, 0,0,0);  \
    a0h = __builtin_amdgcn_mfma_f32_16x16x32_bf16(a_hi[0][3], b3, a0h, 0,0,0);  \
    a1h = __builtin_amdgcn_mfma_f32_16x16x32_bf16(a_hi[1][3], b3, a1h, 0,0,0);  \
    a0l = __builtin_amdgcn_mfma_f32_16x16x32_bf16(a_lo[0][3], b3, a0l, 0,0,0);  \
    a1l = __builtin_amdgcn_mfma_f32_16x16x32_bf16(a_lo[1][3], b3, a1l, 0,0,0);  \
    const float xv = ((unsigned)cc < 32u) ? xs_r[cc & 31] : 0.0f;               \
    {                                                                           \
        const float h0 = tanh_fast(a0h[0] + a0l[0] + biasr[0][0] + winr[0][0] * xv); \
        const float h1 = tanh_fast(a0h[1] + a0l[1] + biasr[0][1] + winr[0][1] * xv); \
        const float h2 = tanh_fast(a0h[2] + a0l[2] + biasr[0][2] + winr[0][2] * xv); \
        const float h3 = tanh_fast(a0h[3] + a0l[3] + biasr[0][3] + winr[0][3] * xv); \
        uint2 pk; pk.x = cvt_pk_bf16(h0, h1); pk.y = cvt_pk_bf16(h2, h3);       \
        *(uint2*)&WB[wroff + cb0] = pk;                                         \
    }                                                                           \
    {                                                                           \
        const float h0 = tanh_fast(a1h[0] + a1l[0] + biasr[1][0] + winr[1][0] * xv); \
        const float h1 = tanh_fast(a1h[1] + a1l[1] + biasr[1][1] + winr[1][1] * xv); \
        const float h2 = tanh_fast(a1h[2] + a1l[2] + biasr[1][2] + winr[1][2] * xv); \
        const float h3 = tanh_fast(a1h[3] + a1l[3] + biasr[1][3] + winr[1][3] * xv); \
        uint2 pk; pk.x = cvt_pk_bf16(h0, h1); pk.y = cvt_pk_bf16(h2, h3);       \
        *(uint2*)&WB[wroff + cb0 + 16] = pk;                                    \
    }                                                                           \
    LGKM_BARRIER();                                                             \
    const uint4 av = *(const uint4*)&WB[fl_off];                                \
    if ((unsigned)ccf < 32u) *(uint4*)actp = av;                                \
    actp += 64; ++cc; ++ccf;                                                    \
} while (0)

    for (int sp = 0; sp < 31; ++sp) {
        STEP(h0buf, h1buf);
        STEP(h1buf, h0buf);
    }
    STEP(h0buf, h1buf);   // step 62
#undef STEP
}

// ---------------------------------------------------------------------------
// k_prep: pre-swizzle w_fc into exact MFMA B-fragment order, bf16, skew-gated.
// Layout: [t]{ [d][ks][lane][j] }, base(t) = off(t)*4096 shorts.
// B[k][n]: k = ks*32 + (lane>>4)*8 + j, n = lane&15 (n>=10 -> 0).
// k -> (r = r0 + (k>>6), o = k&63); w_fc row = ((d*64+o)<<10) + (r<<5) + (t-r).
// ---------------------------------------------------------------------------
__global__ __launch_bounds__(256) void k_prep(
    const float* __restrict__ w_fc,
    unsigned short* __restrict__ wt_swz)
{
    const int t = blockIdx.y;
    const int tid = threadIdx.x;
    const int r0 = SKEW_R0(t), r1 = SKEW_R1(t);
    const int cnt = r1 - r0 + 1;
    const int span = cnt << 10;                    // shorts per d
    int f = blockIdx.x * 2048 + tid * 8;           // short index within t-region
    const int fdst = f;
    if (f >= 4 * span) return;
    int d = 0;
    while (f >= span) { f -= span; ++d; }          // <=3 iters
    const int ks   = f >> 9;
    const int lane = (f >> 3) & 63;
    const int g = lane >> 4, n = lane & 15;
    unsigned int pk[4];
    #pragma unroll
    for (int jj = 0; jj < 4; ++jj) {
        float v[2] = {0.0f, 0.0f};
        #pragma unroll
        for (int h = 0; h < 2; ++h) {
            const int j = jj * 2 + h;
            const int k = ks * 32 + g * 8 + j;
            const int r = r0 + (k >> 6);
            const int o = k & 63;
            const int c = t - r;                   // guaranteed in [0,32)
            if (n < 10)
                v[h] = w_fc[((((size_t)(d * 64 + o)) << 10) + (r << 5) + c) * 10 + n];
        }
        pk[jj] = cvt_pk_bf16(v[0], v[1]);
    }
    uint4 st; st.x = pk[0]; st.y = pk[1]; st.z = pk[2]; st.w = pk[3];
    *(uint4*)(wt_swz + (size_t)SKEW_OFF(t) * 4096 + fdst) = st;
}

// ---------------------------------------------------------------------------
// k_fc: streaming MFMA GEMM over unskewed acts. Block = (t, d, mh); 4 waves =
// 4 M-tiles of 16 batches. A pointer walks +1984 shorts per k-pair (constant).
// ---------------------------------------------------------------------------
__global__ __launch_bounds__(256, 4) void k_fc(
    const unsigned short* __restrict__ acts_c,
    const unsigned short* __restrict__ wt_swz,
    float* __restrict__ partial)
{
    const int tid = threadIdx.x;
    const int blk = blockIdx.x;          // 63*8
    const int t   = blk >> 3;
    const int d   = (blk >> 1) & 3;
    const int mh  = blk & 1;
    const int lane = tid & 63;
    const int wv  = tid >> 6;
    const int g   = lane >> 4;
    const int n   = lane & 15;

    const int r0 = SKEW_R0(t), r1 = SKEW_R1(t);
    const int cnt = r1 - r0 + 1;
    const int off = SKEW_OFF(t);

    const int tb = d * 128 + mh * 64 + wv * 16;
    // A[m=tb+n][k]: k-pair q covers r = r0+q, o-halves; addr linear in q.
    const unsigned short* Ap = acts_c + (size_t)(tb + n) * 65536
                             + (size_t)r0 * 1984 + (size_t)t * 64 + g * 8;
    const unsigned short* Bp = wt_swz
        + ((size_t)off * 4 + (size_t)d * cnt) * 1024 + lane * 8;

    f32x4 acc = {0.f, 0.f, 0.f, 0.f};
    #pragma unroll 2
    for (int q = 0; q < cnt; ++q) {
        const bf16x8 a0  = *(const bf16x8*)(Ap);
        const bf16x8 bb0 = *(const bf16x8*)(Bp);
        const bf16x8 a1  = *(const bf16x8*)(Ap + 32);
        const bf16x8 bb1 = *(const bf16x8*)(Bp + 512);
        acc = __builtin_amdgcn_mfma_f32_16x16x32_bf16(a0, bb0, acc, 0, 0, 0);
        acc = __builtin_amdgcn_mfma_f32_16x16x32_bf16(a1, bb1, acc, 0, 0, 0);
        Ap += 1984;
        Bp += 1024;
    }
    const int batch = tb + g * 4;
    #pragma unroll
    for (int reg = 0; reg < 4; ++reg)
        partial[((size_t)t * 512 + batch + reg) * 16 + n] = acc[reg];
}

// ---------------------------------------------------------------------------
// k_out: logits[n] = b_fc[n] + sum_{t,d} partial; log_softmax.
// ---------------------------------------------------------------------------
__global__ __launch_bounds__(256) void k_out(
    const float* __restrict__ partial,
    const float* __restrict__ b_fc,
    float* __restrict__ out)
{
    __shared__ float lred[252 * 10];
    __shared__ float lgs[10];
    __shared__ float lse;
    const int b = blockIdx.x;
    const int tid = threadIdx.x;
    if (tid < 252) {
        const int t = tid >> 2, d = tid & 3;
        const float* p = partial + ((size_t)t * 512 + d * 128 + b) * 16;
        #pragma unroll
        for (int n2 = 0; n2 < 10; ++n2) lred[tid * 10 + n2] = p[n2];
    }
    __syncthreads();
    if (tid < 10) {
        float s = b_fc[tid];
        for (int i = 0; i < 252; ++i) s += lred[i * 10 + tid];
        lgs[tid] = s;
    }
    __syncthreads();
    if (tid == 0) {
        float m = lgs[0];
        for (int nn = 1; nn < 10; ++nn) m = fmaxf(m, lgs[nn]);
        float ssum = 0.0f;
        for (int nn = 0; nn < 10; ++nn) ssum += __expf(lgs[nn] - m);
        lse = m + __logf(ssum);
    }
    __syncthreads();
    if (tid < 10) out[b * 10 + tid] = lgs[tid] - lse;
}

extern "C" void kernel_launch(void* const* d_in, const int* in_sizes, int n_in,
                              void* d_out, int out_size, void* d_ws, size_t ws_size,
                              hipStream_t stream)
{
    const float* x       = (const float*)d_in[0];
    const float* w_in    = (const float*)d_in[1];
    const float* b_in    = (const float*)d_in[2];
    const float* w_state = (const float*)d_in[3];
    const float* b_state = (const float*)d_in[4];
    const float* w_fc    = (const float*)d_in[5];
    const float* b_fc    = (const float*)d_in[6];
    float* out = (float*)d_out;

    // ws layout: wt_swz 8 MiB | partial 2 MiB @8MiB | acts_c 64 MiB @16MiB
    unsigned short* wt_swz = (unsigned short*)d_ws;
    float* partial = (float*)((char*)d_ws + (size_t)(8u << 20));
    unsigned short* acts_c = (unsigned short*)((char*)d_ws + (size_t)(16u << 20));

    k_prep<<<dim3(64, 63), 256, 0, stream>>>(w_fc, wt_swz);
    k_rnn <<<512, 256, 0, stream>>>(x, w_in, b_in, w_state, b_state, acts_c);
    k_fc  <<<504, 256, 0, stream>>>(acts_c, wt_swz, partial);
    k_out <<<128, 256, 0, stream>>>(partial, b_fc, out);
}